// Round 3
// baseline (547.579 us; speedup 1.0000x reference)
//
#include <hip/hip_runtime.h>
#include <math.h>

#define DM 1024
#define INDIM 512
#define NH 8
#define DH 64
#define LQ 64
#define BATCH 4
#define MX 8192
#define SKV 8256               // MX + LQ
#define MROWS (BATCH * SKV)    // 33024

typedef _Float16 f16;
typedef f16 f16x8 __attribute__((ext_vector_type(8)));
typedef f16 f16x4 __attribute__((ext_vector_type(4)));
typedef float f32x4 __attribute__((ext_vector_type(4)));

// ---------------- LayerNorm: fp32 [rows][1024] -> fp16, scattered into kv_input ----------------
__global__ __launch_bounds__(256) void ln_kernel(const float* __restrict__ src,
        const float* __restrict__ gam, const float* __restrict__ bet,
        f16* __restrict__ dst, f16* __restrict__ dst2,
        int rpb_in, int dst_off)
{
    int r = blockIdx.x;
    int tid = threadIdx.x;
    int b = r / rpb_in, m = r % rpb_in;
    const float4 v = *(const float4*)(src + (size_t)r * DM + tid * 4);
    float s = v.x + v.y + v.z + v.w;
    float q = v.x * v.x + v.y * v.y + v.z * v.z + v.w * v.w;
    for (int off = 32; off; off >>= 1) { s += __shfl_xor(s, off); q += __shfl_xor(q, off); }
    __shared__ float ps[4], pq[4];
    int w = tid >> 6;
    if ((tid & 63) == 0) { ps[w] = s; pq[w] = q; }
    __syncthreads();
    s = ps[0] + ps[1] + ps[2] + ps[3];
    q = pq[0] + pq[1] + pq[2] + pq[3];
    float mean = s * (1.f / DM);
    float var = q * (1.f / DM) - mean * mean;
    float rstd = rsqrtf(var + 1e-5f);
    const float4 gg = *(const float4*)(gam + tid * 4);
    const float4 bb = *(const float4*)(bet + tid * 4);
    f16x4 o;
    o[0] = (f16)((v.x - mean) * rstd * gg.x + bb.x);
    o[1] = (f16)((v.y - mean) * rstd * gg.y + bb.y);
    o[2] = (f16)((v.z - mean) * rstd * gg.z + bb.z);
    o[3] = (f16)((v.w - mean) * rstd * gg.w + bb.w);
    size_t drow = (size_t)b * SKV + dst_off + m;
    *(f16x4*)(dst + drow * DM + tid * 4) = o;
    if (dst2) *(f16x4*)(dst2 + (size_t)r * DM + tid * 4) = o;
}

// ---------------- Weight transpose: fp32 [R][C] -> fp16 [C][R], optional scale ----------------
__global__ __launch_bounds__(256) void transpose_w(const float* __restrict__ src,
        f16* __restrict__ dst, int R, int C, float scale)
{
    __shared__ float tile[32][33];
    int c0 = blockIdx.x * 32, r0 = blockIdx.y * 32;
    int tx = threadIdx.x & 31;
    int ty = threadIdx.x >> 5;  // 0..7
    #pragma unroll
    for (int k = 0; k < 4; k++)
        tile[ty + k * 8][tx] = src[(size_t)(r0 + ty + k * 8) * C + c0 + tx];
    __syncthreads();
    #pragma unroll
    for (int k = 0; k < 4; k++)
        dst[(size_t)(c0 + ty + k * 8) * R + r0 + tx] = (f16)(tile[tx][ty + k * 8] * scale);
}

// ---------------- Generic fp16 GEMM: C[M][N] = A[M][K] * Bt[N][K]^T ----------------
// MODE 1: C -> fp32 Cf.
// MODE 2: kv split (cols<512: k -> k hi/lo pair; cols>=512: v -> vT[b*8+h][d][key], fp16)
// MODE 3: C -> fp16 hi/lo pair (q path)
template<int MODE>
__global__ __launch_bounds__(256) void gemm_bt(const f16* __restrict__ A, const f16* __restrict__ Bt,
        f16* __restrict__ Chi, f16* __restrict__ Clo,
        float* __restrict__ Cf, f16* __restrict__ vT,
        int M, int N, int K)
{
    __shared__ f16 As[128 * 40];
    __shared__ f16 Bs[128 * 40];
    int tid = threadIdx.x;
    int w = tid >> 6, l = tid & 63, l15 = l & 15, gq = l >> 4;
    int wr = w >> 1, wc = w & 1;
    int bm = blockIdx.x, bn = blockIdx.y;
    const f16* Ap = A + (size_t)(bm * 128 + (tid >> 1)) * K + (tid & 1) * 16;
    const f16* Bp = Bt + (size_t)(bn * 128 + (tid >> 1)) * K + (tid & 1) * 16;
    f16* As_w = &As[(tid >> 1) * 40 + (tid & 1) * 16];
    f16* Bs_w = &Bs[(tid >> 1) * 40 + (tid & 1) * 16];
    f32x4 acc[4][4] = {};
    for (int k0 = 0; k0 < K; k0 += 32) {
        f16x8 a0 = *(const f16x8*)(Ap + k0);
        f16x8 a1 = *(const f16x8*)(Ap + k0 + 8);
        f16x8 b0 = *(const f16x8*)(Bp + k0);
        f16x8 b1 = *(const f16x8*)(Bp + k0 + 8);
        __syncthreads();
        *(f16x8*)As_w = a0; *(f16x8*)(As_w + 8) = a1;
        *(f16x8*)Bs_w = b0; *(f16x8*)(Bs_w + 8) = b1;
        __syncthreads();
        f16x8 af[4], bfr[4];
        #pragma unroll
        for (int mm = 0; mm < 4; mm++)
            af[mm] = *(const f16x8*)&As[(wr * 64 + mm * 16 + l15) * 40 + gq * 8];
        #pragma unroll
        for (int nn = 0; nn < 4; nn++)
            bfr[nn] = *(const f16x8*)&Bs[(wc * 64 + nn * 16 + l15) * 40 + gq * 8];
        #pragma unroll
        for (int mm = 0; mm < 4; mm++)
            #pragma unroll
            for (int nn = 0; nn < 4; nn++)
                acc[mm][nn] = __builtin_amdgcn_mfma_f32_16x16x32_f16(af[mm], bfr[nn], acc[mm][nn], 0, 0, 0);
    }
    int rowb = bm * 128 + wr * 64 + gq * 4;
    int colb = bn * 128 + wc * 64 + l15;
    #pragma unroll
    for (int mm = 0; mm < 4; mm++)
    #pragma unroll
    for (int nn = 0; nn < 4; nn++)
    #pragma unroll
    for (int i = 0; i < 4; i++) {
        int row = rowb + mm * 16 + i;
        int col = colb + nn * 16;
        float v = acc[mm][nn][i];
        if (MODE == 1) {
            Cf[(size_t)row * N + col] = v;
        } else if (MODE == 3) {
            f16 hi = (f16)v;
            Chi[(size_t)row * N + col] = hi;
            Clo[(size_t)row * N + col] = (f16)(v - (float)hi);
        } else {
            if (col < INDIM) {
                f16 hi = (f16)v;
                Chi[(size_t)row * INDIM + col] = hi;
                Clo[(size_t)row * INDIM + col] = (f16)(v - (float)hi);
            } else {
                int b = row / SKV; int key = row - b * SKV;
                int hd = col - INDIM;
                vT[(size_t)((b * NH + (hd >> 6)) * DH + (hd & 63)) * SKV + key] = (f16)v;
            }
        }
    }
}

// ---------------- Flash attention: 1 block per (b,h), 8 waves, interleaved 32-key tiles ----------------
// QK^T uses split-fp16: S = k_hi*q_hi + k_hi*q_lo + k_lo*q_hi  (fp32-accurate sim)
__global__ __launch_bounds__(512) void attn_kernel(const f16* __restrict__ q_hi, const f16* __restrict__ q_lo,
        const f16* __restrict__ k_hi, const f16* __restrict__ k_lo,
        const f16* __restrict__ vT, f16* __restrict__ attn_out)
{
    __shared__ f16 P_lds[8][64][40];
    __shared__ float O_sum[64][64];
    __shared__ float m_lds[8][64];
    __shared__ float l_lds[8][64];
    int bh = blockIdx.x; int b = bh >> 3, h = bh & 7;
    int tid = threadIdx.x, w = tid >> 6, l = tid & 63, l15 = l & 15, gq = l >> 4;
    for (int i = tid; i < 64 * 64; i += 512) ((float*)O_sum)[i] = 0.f;
    f16x8 qfh[4][2], qfl[4][2];
    #pragma unroll
    for (int nb = 0; nb < 4; nb++)
        #pragma unroll
        for (int dh = 0; dh < 2; dh++) {
            size_t off = (size_t)(b * LQ + nb * 16 + l15) * INDIM + h * DH + dh * 32 + gq * 8;
            qfh[nb][dh] = *(const f16x8*)&q_hi[off];
            qfl[nb][dh] = *(const f16x8*)&q_lo[off];
        }
    const f16* kbh = k_hi + (size_t)b * SKV * INDIM + h * DH;
    const f16* kbl = k_lo + (size_t)b * SKV * INDIM + h * DH;
    const f16* vb = vT + (size_t)bh * DH * SKV;
    f32x4 accO[4][4] = {};
    float m_st[4] = {-1e30f, -1e30f, -1e30f, -1e30f};
    float l_st[4] = {0.f, 0.f, 0.f, 0.f};
    __syncthreads();
    for (int t = w; t < 258; t += 8) {
        int key0 = t * 32;
        f32x4 S[2][4] = {};
        f16x8 kah[2][2], kal[2][2];
        #pragma unroll
        for (int kbi = 0; kbi < 2; kbi++)
            #pragma unroll
            for (int dh = 0; dh < 2; dh++) {
                size_t off = (size_t)(key0 + kbi * 16 + l15) * INDIM + dh * 32 + gq * 8;
                kah[kbi][dh] = *(const f16x8*)&kbh[off];
                kal[kbi][dh] = *(const f16x8*)&kbl[off];
            }
        #pragma unroll
        for (int kbi = 0; kbi < 2; kbi++)
            #pragma unroll
            for (int nb = 0; nb < 4; nb++) {
                S[kbi][nb] = __builtin_amdgcn_mfma_f32_16x16x32_f16(kah[kbi][0], qfh[nb][0], S[kbi][nb], 0, 0, 0);
                S[kbi][nb] = __builtin_amdgcn_mfma_f32_16x16x32_f16(kah[kbi][1], qfh[nb][1], S[kbi][nb], 0, 0, 0);
                S[kbi][nb] = __builtin_amdgcn_mfma_f32_16x16x32_f16(kah[kbi][0], qfl[nb][0], S[kbi][nb], 0, 0, 0);
                S[kbi][nb] = __builtin_amdgcn_mfma_f32_16x16x32_f16(kah[kbi][1], qfl[nb][1], S[kbi][nb], 0, 0, 0);
                S[kbi][nb] = __builtin_amdgcn_mfma_f32_16x16x32_f16(kal[kbi][0], qfh[nb][0], S[kbi][nb], 0, 0, 0);
                S[kbi][nb] = __builtin_amdgcn_mfma_f32_16x16x32_f16(kal[kbi][1], qfh[nb][1], S[kbi][nb], 0, 0, 0);
            }
        #pragma unroll
        for (int nb = 0; nb < 4; nb++) {
            float tm = -1e30f;
            #pragma unroll
            for (int kbi = 0; kbi < 2; kbi++)
                #pragma unroll
                for (int i = 0; i < 4; i++) tm = fmaxf(tm, S[kbi][nb][i]);
            tm = fmaxf(tm, __shfl_xor(tm, 16));
            tm = fmaxf(tm, __shfl_xor(tm, 32));
            float nm = fmaxf(m_st[nb], tm);
            float corr = __expf(m_st[nb] - nm);
            m_st[nb] = nm;
            float rs = 0.f;
            #pragma unroll
            for (int kbi = 0; kbi < 2; kbi++) {
                f16x4 pk;
                #pragma unroll
                for (int i = 0; i < 4; i++) {
                    float p = __expf(S[kbi][nb][i] - nm);
                    rs += p;
                    pk[i] = (f16)p;
                }
                *(f16x4*)&P_lds[w][nb * 16 + l15][kbi * 16 + gq * 4] = pk;
            }
            rs += __shfl_xor(rs, 16);
            rs += __shfl_xor(rs, 32);
            l_st[nb] = l_st[nb] * corr + rs;
            #pragma unroll
            for (int db = 0; db < 4; db++) accO[db][nb] *= corr;
        }
        #pragma unroll
        for (int db = 0; db < 4; db++) {
            f16x8 va = *(const f16x8*)&vb[(size_t)(db * 16 + l15) * SKV + key0 + gq * 8];
            #pragma unroll
            for (int nb = 0; nb < 4; nb++) {
                f16x8 pb = *(const f16x8*)&P_lds[w][nb * 16 + l15][gq * 8];
                accO[db][nb] = __builtin_amdgcn_mfma_f32_16x16x32_f16(va, pb, accO[db][nb], 0, 0, 0);
            }
        }
    }
    if (gq == 0) {
        #pragma unroll
        for (int nb = 0; nb < 4; nb++) {
            m_lds[w][nb * 16 + l15] = m_st[nb];
            l_lds[w][nb * 16 + l15] = l_st[nb];
        }
    }
    __syncthreads();
    #pragma unroll
    for (int nb = 0; nb < 4; nb++) {
        int qrow = nb * 16 + l15;
        float Mx = -1e30f;
        #pragma unroll
        for (int ww = 0; ww < 8; ww++) Mx = fmaxf(Mx, m_lds[ww][qrow]);
        float f = __expf(m_st[nb] - Mx);
        #pragma unroll
        for (int db = 0; db < 4; db++)
            #pragma unroll
            for (int i = 0; i < 4; i++)
                atomicAdd(&O_sum[db * 16 + gq * 4 + i][qrow], accO[db][nb][i] * f);
    }
    __syncthreads();
    {
        int qrow = tid >> 3, d0 = (tid & 7) * 8;
        float Mx = -1e30f;
        #pragma unroll
        for (int ww = 0; ww < 8; ww++) Mx = fmaxf(Mx, m_lds[ww][qrow]);
        float Ls = 0.f;
        #pragma unroll
        for (int ww = 0; ww < 8; ww++) Ls += l_lds[ww][qrow] * __expf(m_lds[ww][qrow] - Mx);
        float inv = 1.f / Ls;
        f16x8 o;
        #pragma unroll
        for (int j = 0; j < 8; j++) o[j] = (f16)(O_sum[d0 + j][qrow] * inv);
        *(f16x8*)&attn_out[(size_t)(b * LQ + qrow) * INDIM + h * DH + d0] = o;
    }
}

extern "C" void kernel_launch(void* const* d_in, const int* in_sizes, int n_in,
                              void* d_out, int out_size, void* d_ws, size_t ws_size,
                              hipStream_t stream)
{
    const float* x    = (const float*)d_in[0];
    const float* lat  = (const float*)d_in[1];
    const float* Wq   = (const float*)d_in[2];
    const float* Wkv  = (const float*)d_in[3];
    const float* Wout = (const float*)d_in[4];
    const float* gm   = (const float*)d_in[5];
    const float* bm   = (const float*)d_in[6];
    const float* gl   = (const float*)d_in[7];
    const float* bl   = (const float*)d_in[8];
    float* out = (float*)d_out;

    char* ws = (char*)d_ws;
    size_t off = 0;
    auto alloc = [&](size_t bytes) {
        char* p = ws + off;
        off += (bytes + 255) & ~(size_t)255;
        return p;
    };
    f16* kv_in  = (f16*)alloc((size_t)MROWS * DM * 2);       // layernormed [xn;ln] fp16
    f16* k_hi   = (f16*)alloc((size_t)MROWS * INDIM * 2);    // k split hi
    f16* k_lo   = (f16*)alloc((size_t)MROWS * INDIM * 2);    // k split lo
    f16* vT     = (f16*)alloc((size_t)BATCH * NH * DH * SKV * 2); // v transposed [bh][d][key]
    f16* q_in   = (f16*)alloc((size_t)BATCH * LQ * DM * 2);  // ln(latents) compact
    f16* q_hi   = (f16*)alloc((size_t)BATCH * LQ * INDIM * 2);
    f16* q_lo   = (f16*)alloc((size_t)BATCH * LQ * INDIM * 2);
    f16* wq_t   = (f16*)alloc((size_t)INDIM * DM * 2);
    f16* wkv_t  = (f16*)alloc((size_t)DM * DM * 2);
    f16* wout_t = (f16*)alloc((size_t)DM * INDIM * 2);
    f16* attn_o = (f16*)alloc((size_t)BATCH * LQ * INDIM * 2);

    // weight transposes (fold q scale sqrt(64)=8 into Wq)
    transpose_w<<<dim3(INDIM / 32, DM / 32), 256, 0, stream>>>(Wq, wq_t, DM, INDIM, 8.0f);
    transpose_w<<<dim3(DM / 32, DM / 32), 256, 0, stream>>>(Wkv, wkv_t, DM, DM, 1.0f);
    transpose_w<<<dim3(DM / 32, INDIM / 32), 256, 0, stream>>>(Wout, wout_t, INDIM, DM, 1.0f);
    // layernorms
    ln_kernel<<<BATCH * MX, 256, 0, stream>>>(x, gm, bm, kv_in, nullptr, MX, 0);
    ln_kernel<<<BATCH * LQ, 256, 0, stream>>>(lat, gl, bl, kv_in, q_in, LQ, MX);
    // q = ln(latents) @ Wq * 8  -> hi/lo split
    gemm_bt<3><<<dim3(2, INDIM / 128), 256, 0, stream>>>(q_in, wq_t, q_hi, q_lo, nullptr, nullptr,
                                                         BATCH * LQ, INDIM, DM);
    // kv = [xn;ln] @ Wkv  (k -> hi/lo split, v -> vT)
    gemm_bt<2><<<dim3(MROWS / 128, DM / 128), 256, 0, stream>>>(kv_in, wkv_t, k_hi, k_lo, nullptr, vT,
                                                                MROWS, DM, DM);
    // attention
    attn_kernel<<<BATCH * NH, 512, 0, stream>>>(q_hi, q_lo, k_hi, k_lo, vT, attn_o);
    // out = attn_o @ Wout
    gemm_bt<1><<<dim3(2, DM / 128), 256, 0, stream>>>(attn_o, wout_t, nullptr, nullptr, out, nullptr,
                                                      BATCH * LQ, DM, INDIM);
}

// Round 6
// 477.030 us; speedup vs baseline: 1.1479x; 1.1479x over previous
//
#include <hip/hip_runtime.h>
#include <math.h>

#define DM 1024
#define INDIM 512
#define NH 8
#define DH 64
#define LQ 64
#define BATCH 4
#define MX 8192
#define SKV 8256               // MX + LQ
#define MROWS (BATCH * SKV)    // 33024
#define NBH (BATCH * NH)       // 32
#define NT 258                 // 32-key tiles in SKV
#define NCHUNK 8
#define TPC 33                 // ceil(NT / NCHUNK)

typedef _Float16 f16;
typedef f16 f16x8 __attribute__((ext_vector_type(8)));
typedef f16 f16x4 __attribute__((ext_vector_type(4)));
typedef float f32x4 __attribute__((ext_vector_type(4)));

typedef __attribute__((address_space(1))) const unsigned int gu32;
typedef __attribute__((address_space(3))) unsigned int lu32;
__device__ __forceinline__ void gload16(const f16* g, f16* l) {
    // async global->LDS DMA: wave-uniform LDS base, lane i lands at base + i*16B
    __builtin_amdgcn_global_load_lds((gu32*)g, (lu32*)l, 16, 0, 0);
}

// ---------------- LayerNorm: fp32 [rows][1024] -> fp16, scattered into kv_input ----------------
__global__ __launch_bounds__(256) void ln_kernel(const float* __restrict__ src,
        const float* __restrict__ gam, const float* __restrict__ bet,
        f16* __restrict__ dst, f16* __restrict__ dst2,
        int rpb_in, int dst_off)
{
    int r = blockIdx.x;
    int tid = threadIdx.x;
    int b = r / rpb_in, m = r % rpb_in;
    const float4 v = *(const float4*)(src + (size_t)r * DM + tid * 4);
    float s = v.x + v.y + v.z + v.w;
    float q = v.x * v.x + v.y * v.y + v.z * v.z + v.w * v.w;
    for (int off = 32; off; off >>= 1) { s += __shfl_xor(s, off); q += __shfl_xor(q, off); }
    __shared__ float ps[4], pq[4];
    int w = tid >> 6;
    if ((tid & 63) == 0) { ps[w] = s; pq[w] = q; }
    __syncthreads();
    s = ps[0] + ps[1] + ps[2] + ps[3];
    q = pq[0] + pq[1] + pq[2] + pq[3];
    float mean = s * (1.f / DM);
    float var = q * (1.f / DM) - mean * mean;
    float rstd = rsqrtf(var + 1e-5f);
    const float4 gg = *(const float4*)(gam + tid * 4);
    const float4 bb = *(const float4*)(bet + tid * 4);
    f16x4 o;
    o[0] = (f16)((v.x - mean) * rstd * gg.x + bb.x);
    o[1] = (f16)((v.y - mean) * rstd * gg.y + bb.y);
    o[2] = (f16)((v.z - mean) * rstd * gg.z + bb.z);
    o[3] = (f16)((v.w - mean) * rstd * gg.w + bb.w);
    size_t drow = (size_t)b * SKV + dst_off + m;
    *(f16x4*)(dst + drow * DM + tid * 4) = o;
    if (dst2) *(f16x4*)(dst2 + (size_t)r * DM + tid * 4) = o;
}

// ---------------- Weight transpose: fp32 [R][C] -> fp16 [C][R], optional scale ----------------
__global__ __launch_bounds__(256) void transpose_w(const float* __restrict__ src,
        f16* __restrict__ dst, int R, int C, float scale)
{
    __shared__ float tile[32][33];
    int c0 = blockIdx.x * 32, r0 = blockIdx.y * 32;
    int tx = threadIdx.x & 31;
    int ty = threadIdx.x >> 5;  // 0..7
    #pragma unroll
    for (int k = 0; k < 4; k++)
        tile[ty + k * 8][tx] = src[(size_t)(r0 + ty + k * 8) * C + c0 + tx];
    __syncthreads();
    #pragma unroll
    for (int k = 0; k < 4; k++)
        dst[(size_t)(c0 + ty + k * 8) * R + r0 + tx] = (f16)(tile[tx][ty + k * 8] * scale);
}

// ---------------- Generic fp16 GEMM (m97 structure): C[M][N] = A[M][K] * Bt[N][K]^T ----------------
// global_load_lds width-16 staging into linear LDS [128][32] (64B rows), 2 barriers / K-step.
// MODE 1: C -> fp32 Cf.
// MODE 2: kv split (cols<512: k -> k hi/lo pair; cols>=512: v -> vT[b*8+h][d][key], fp16)
// MODE 3: C -> fp16 hi/lo pair (q path)
template<int MODE>
__global__ __launch_bounds__(256) void gemm_bt(const f16* __restrict__ A, const f16* __restrict__ Bt,
        f16* __restrict__ Chi, f16* __restrict__ Clo,
        float* __restrict__ Cf, f16* __restrict__ vT,
        int M, int N, int K)
{
    __shared__ f16 As[128 * 32];
    __shared__ f16 Bs[128 * 32];
    int tid = threadIdx.x;
    int w = tid >> 6, l = tid & 63, l15 = l & 15, gq = l >> 4;
    int wr = w >> 1, wc = w & 1;
    int bm = blockIdx.x, bn = blockIdx.y;
    // staging: wave w covers rows [w*32, w*32+32); inst j=0 rows +0..15, j=1 rows +16..31.
    // lane l -> row w*32 + j*16 + (l>>2), 16B chunk (l&3). LDS linear row*64B + chunk*16B.
    const f16* gA = A + (size_t)(bm * 128 + w * 32 + (l >> 2)) * K + (l & 3) * 8;
    const f16* gB = Bt + (size_t)(bn * 128 + w * 32 + (l >> 2)) * K + (l & 3) * 8;
    f16* lA0 = As + w * 1024;          // rows w*32..: 16 rows * 32 f16
    f16* lA1 = As + w * 1024 + 512;
    f16* lB0 = Bs + w * 1024;
    f16* lB1 = Bs + w * 1024 + 512;
    const size_t j1 = (size_t)16 * K;
    f32x4 acc[4][4] = {};
    for (int k0 = 0; k0 < K; k0 += 32) {
        __syncthreads();               // readers of previous tile done
        gload16(gA + k0, lA0);
        gload16(gA + k0 + j1, lA1);
        gload16(gB + k0, lB0);
        gload16(gB + k0 + j1, lB1);
        __syncthreads();               // compiler drains vmcnt before barrier -> LDS tile ready
        f16x8 af[4], bfr[4];
        #pragma unroll
        for (int mm = 0; mm < 4; mm++)
            af[mm] = *(const f16x8*)&As[(wr * 64 + mm * 16 + l15) * 32 + gq * 8];
        #pragma unroll
        for (int nn = 0; nn < 4; nn++)
            bfr[nn] = *(const f16x8*)&Bs[(wc * 64 + nn * 16 + l15) * 32 + gq * 8];
        #pragma unroll
        for (int mm = 0; mm < 4; mm++)
            #pragma unroll
            for (int nn = 0; nn < 4; nn++)
                acc[mm][nn] = __builtin_amdgcn_mfma_f32_16x16x32_f16(af[mm], bfr[nn], acc[mm][nn], 0, 0, 0);
    }
    int rowb = bm * 128 + wr * 64 + gq * 4;
    int colb = bn * 128 + wc * 64 + l15;
    #pragma unroll
    for (int mm = 0; mm < 4; mm++)
    #pragma unroll
    for (int nn = 0; nn < 4; nn++)
    #pragma unroll
    for (int i = 0; i < 4; i++) {
        int row = rowb + mm * 16 + i;
        int col = colb + nn * 16;
        float v = acc[mm][nn][i];
        if (MODE == 1) {
            Cf[(size_t)row * N + col] = v;
        } else if (MODE == 3) {
            f16 hi = (f16)v;
            Chi[(size_t)row * N + col] = hi;
            Clo[(size_t)row * N + col] = (f16)(v - (float)hi);
        } else {
            if (col < INDIM) {
                f16 hi = (f16)v;
                Chi[(size_t)row * INDIM + col] = hi;
                Clo[(size_t)row * INDIM + col] = (f16)(v - (float)hi);
            } else {
                int b = row / SKV; int key = row - b * SKV;
                int hd = col - INDIM;
                vT[(size_t)((b * NH + (hd >> 6)) * DH + (hd & 63)) * SKV + key] = (f16)v;
            }
        }
    }
}

// ---------------- Flash attention, split-K: 1 block per (b,h,chunk), 8 waves ----------------
// QK^T uses split-fp16: S = k_hi*q_hi + k_hi*q_lo + k_lo*q_hi  (fp32-accurate sim)
// Writes per-chunk partials (m, l, unnormalized O) for a separate merge kernel.
__global__ __launch_bounds__(512) void attn_kernel(const f16* __restrict__ q_hi, const f16* __restrict__ q_lo,
        const f16* __restrict__ k_hi, const f16* __restrict__ k_lo,
        const f16* __restrict__ vT,
        float* __restrict__ pO, float* __restrict__ pm, float* __restrict__ pl)
{
    __shared__ f16 P_lds[8][64][40];
    __shared__ float O_sum[64][64];
    __shared__ float m_lds[8][64];
    __shared__ float l_lds[8][64];
    int bh = blockIdx.x & (NBH - 1);
    int chunk = blockIdx.x >> 5;
    int b = bh >> 3, h = bh & 7;
    int cstart = chunk * TPC;
    int cend = cstart + TPC; if (cend > NT) cend = NT;
    int tid = threadIdx.x, w = tid >> 6, l = tid & 63, l15 = l & 15, gq = l >> 4;
    for (int i = tid; i < 64 * 64; i += 512) ((float*)O_sum)[i] = 0.f;
    f16x8 qfh[4][2], qfl[4][2];
    #pragma unroll
    for (int nb = 0; nb < 4; nb++)
        #pragma unroll
        for (int dh = 0; dh < 2; dh++) {
            size_t off = (size_t)(b * LQ + nb * 16 + l15) * INDIM + h * DH + dh * 32 + gq * 8;
            qfh[nb][dh] = *(const f16x8*)&q_hi[off];
            qfl[nb][dh] = *(const f16x8*)&q_lo[off];
        }
    const f16* kbh = k_hi + (size_t)b * SKV * INDIM + h * DH;
    const f16* kbl = k_lo + (size_t)b * SKV * INDIM + h * DH;
    const f16* vb = vT + (size_t)bh * DH * SKV;
    f32x4 accO[4][4] = {};
    float m_st[4] = {-1e30f, -1e30f, -1e30f, -1e30f};
    float l_st[4] = {0.f, 0.f, 0.f, 0.f};
    __syncthreads();
    for (int t = cstart + w; t < cend; t += 8) {
        int key0 = t * 32;
        f32x4 S[2][4] = {};
        f16x8 kah[2][2], kal[2][2];
        #pragma unroll
        for (int kbi = 0; kbi < 2; kbi++)
            #pragma unroll
            for (int dh = 0; dh < 2; dh++) {
                size_t off = (size_t)(key0 + kbi * 16 + l15) * INDIM + dh * 32 + gq * 8;
                kah[kbi][dh] = *(const f16x8*)&kbh[off];
                kal[kbi][dh] = *(const f16x8*)&kbl[off];
            }
        #pragma unroll
        for (int kbi = 0; kbi < 2; kbi++)
            #pragma unroll
            for (int nb = 0; nb < 4; nb++) {
                S[kbi][nb] = __builtin_amdgcn_mfma_f32_16x16x32_f16(kah[kbi][0], qfh[nb][0], S[kbi][nb], 0, 0, 0);
                S[kbi][nb] = __builtin_amdgcn_mfma_f32_16x16x32_f16(kah[kbi][1], qfh[nb][1], S[kbi][nb], 0, 0, 0);
                S[kbi][nb] = __builtin_amdgcn_mfma_f32_16x16x32_f16(kah[kbi][0], qfl[nb][0], S[kbi][nb], 0, 0, 0);
                S[kbi][nb] = __builtin_amdgcn_mfma_f32_16x16x32_f16(kah[kbi][1], qfl[nb][1], S[kbi][nb], 0, 0, 0);
                S[kbi][nb] = __builtin_amdgcn_mfma_f32_16x16x32_f16(kal[kbi][0], qfh[nb][0], S[kbi][nb], 0, 0, 0);
                S[kbi][nb] = __builtin_amdgcn_mfma_f32_16x16x32_f16(kal[kbi][1], qfh[nb][1], S[kbi][nb], 0, 0, 0);
            }
        #pragma unroll
        for (int nb = 0; nb < 4; nb++) {
            float tm = -1e30f;
            #pragma unroll
            for (int kbi = 0; kbi < 2; kbi++)
                #pragma unroll
                for (int i = 0; i < 4; i++) tm = fmaxf(tm, S[kbi][nb][i]);
            tm = fmaxf(tm, __shfl_xor(tm, 16));
            tm = fmaxf(tm, __shfl_xor(tm, 32));
            float nm = fmaxf(m_st[nb], tm);
            float corr = __expf(m_st[nb] - nm);
            m_st[nb] = nm;
            float rs = 0.f;
            #pragma unroll
            for (int kbi = 0; kbi < 2; kbi++) {
                f16x4 pk;
                #pragma unroll
                for (int i = 0; i < 4; i++) {
                    float p = __expf(S[kbi][nb][i] - nm);
                    rs += p;
                    pk[i] = (f16)p;
                }
                *(f16x4*)&P_lds[w][nb * 16 + l15][kbi * 16 + gq * 4] = pk;
            }
            rs += __shfl_xor(rs, 16);
            rs += __shfl_xor(rs, 32);
            l_st[nb] = l_st[nb] * corr + rs;
            #pragma unroll
            for (int db = 0; db < 4; db++) accO[db][nb] *= corr;
        }
        #pragma unroll
        for (int db = 0; db < 4; db++) {
            f16x8 va = *(const f16x8*)&vb[(size_t)(db * 16 + l15) * SKV + key0 + gq * 8];
            #pragma unroll
            for (int nb = 0; nb < 4; nb++) {
                f16x8 pb = *(const f16x8*)&P_lds[w][nb * 16 + l15][gq * 8];
                accO[db][nb] = __builtin_amdgcn_mfma_f32_16x16x32_f16(va, pb, accO[db][nb], 0, 0, 0);
            }
        }
    }
    if (gq == 0) {
        #pragma unroll
        for (int nb = 0; nb < 4; nb++) {
            m_lds[w][nb * 16 + l15] = m_st[nb];
            l_lds[w][nb * 16 + l15] = l_st[nb];
        }
    }
    __syncthreads();
    #pragma unroll
    for (int nb = 0; nb < 4; nb++) {
        int qrow = nb * 16 + l15;
        float Mx = -1e30f;
        #pragma unroll
        for (int ww = 0; ww < 8; ww++) Mx = fmaxf(Mx, m_lds[ww][qrow]);
        float f = __expf(m_st[nb] - Mx);
        #pragma unroll
        for (int db = 0; db < 4; db++)
            #pragma unroll
            for (int i = 0; i < 4; i++)
                atomicAdd(&O_sum[db * 16 + gq * 4 + i][qrow], accO[db][nb][i] * f);
    }
    __syncthreads();
    {
        int qrow = tid >> 3, d0 = (tid & 7) * 8;
        float Mx = -1e30f;
        #pragma unroll
        for (int ww = 0; ww < 8; ww++) Mx = fmaxf(Mx, m_lds[ww][qrow]);
        float Ls = 0.f;
        #pragma unroll
        for (int ww = 0; ww < 8; ww++) Ls += l_lds[ww][qrow] * __expf(m_lds[ww][qrow] - Mx);
        size_t base = ((size_t)(bh * NCHUNK + chunk) * 64 + qrow) * 64 + d0;
        float4 o0, o1;
        o0.x = O_sum[d0 + 0][qrow]; o0.y = O_sum[d0 + 1][qrow];
        o0.z = O_sum[d0 + 2][qrow]; o0.w = O_sum[d0 + 3][qrow];
        o1.x = O_sum[d0 + 4][qrow]; o1.y = O_sum[d0 + 5][qrow];
        o1.z = O_sum[d0 + 6][qrow]; o1.w = O_sum[d0 + 7][qrow];
        *(float4*)&pO[base] = o0;
        *(float4*)&pO[base + 4] = o1;
        if (d0 == 0) {
            pm[(bh * NCHUNK + chunk) * 64 + qrow] = Mx;
            pl[(bh * NCHUNK + chunk) * 64 + qrow] = Ls;
        }
    }
}

// ---------------- Merge split-K partials -> attn_o fp16 ----------------
__global__ __launch_bounds__(256) void attn_merge(const float* __restrict__ pO,
        const float* __restrict__ pm, const float* __restrict__ pl, f16* __restrict__ attn_out)
{
    int bh = blockIdx.x; int b = bh >> 3, h = bh & 7;
    int tid = threadIdx.x;
    int row = tid >> 2, dseg = tid & 3;   // 16 dims per thread
    float pmv[NCHUNK];
    float mx = -1e30f;
    #pragma unroll
    for (int c = 0; c < NCHUNK; c++) {
        pmv[c] = pm[(bh * NCHUNK + c) * 64 + row];
        mx = fmaxf(mx, pmv[c]);
    }
    float L = 0.f;
    float wgt[NCHUNK];
    #pragma unroll
    for (int c = 0; c < NCHUNK; c++) {
        wgt[c] = __expf(pmv[c] - mx);
        L += pl[(bh * NCHUNK + c) * 64 + row] * wgt[c];
    }
    float inv = 1.f / L;
    float acc[16] = {};
    #pragma unroll
    for (int c = 0; c < NCHUNK; c++) {
        const float* p = &pO[((size_t)(bh * NCHUNK + c) * 64 + row) * 64 + dseg * 16];
        float wc = wgt[c];
        #pragma unroll
        for (int jj = 0; jj < 4; jj++) {
            float4 a = *(const float4*)(p + jj * 4);
            acc[jj * 4 + 0] += a.x * wc; acc[jj * 4 + 1] += a.y * wc;
            acc[jj * 4 + 2] += a.z * wc; acc[jj * 4 + 3] += a.w * wc;
        }
    }
    f16 o[16];
    #pragma unroll
    for (int j = 0; j < 16; j++) o[j] = (f16)(acc[j] * inv);
    f16* dst = &attn_out[(size_t)(b * LQ + row) * INDIM + h * DH + dseg * 16];
    *(f16x8*)dst = *(f16x8*)&o[0];
    *(f16x8*)(dst + 8) = *(f16x8*)&o[8];
}

extern "C" void kernel_launch(void* const* d_in, const int* in_sizes, int n_in,
                              void* d_out, int out_size, void* d_ws, size_t ws_size,
                              hipStream_t stream)
{
    const float* x    = (const float*)d_in[0];
    const float* lat  = (const float*)d_in[1];
    const float* Wq   = (const float*)d_in[2];
    const float* Wkv  = (const float*)d_in[3];
    const float* Wout = (const float*)d_in[4];
    const float* gm   = (const float*)d_in[5];
    const float* bm   = (const float*)d_in[6];
    const float* gl   = (const float*)d_in[7];
    const float* bl   = (const float*)d_in[8];
    float* out = (float*)d_out;

    char* ws = (char*)d_ws;
    size_t off = 0;
    auto alloc = [&](size_t bytes) {
        char* p = ws + off;
        off += (bytes + 255) & ~(size_t)255;
        return p;
    };
    // NOTE (round 5 post-mortem): total workspace footprint must stay <= the
    // round-3-proven 174.6 MB; round 5 appended pO/pm/pl past that and the OOB
    // writes corrupted a neighboring allocation (first launch OK, all later
    // launches fail). Fix: alias pO/pm/pl into kv_in's region — kv_in is dead
    // after gemm_bt<2>, pO/pm/pl are only written by attn_kernel (later).
    f16* kv_in  = (f16*)alloc((size_t)MROWS * DM * 2);       // layernormed [xn;ln] fp16
    f16* k_hi   = (f16*)alloc((size_t)MROWS * INDIM * 2);    // k split hi
    f16* k_lo   = (f16*)alloc((size_t)MROWS * INDIM * 2);    // k split lo
    f16* vT     = (f16*)alloc((size_t)BATCH * NH * DH * SKV * 2); // v transposed [bh][d][key]
    f16* q_in   = (f16*)alloc((size_t)BATCH * LQ * DM * 2);  // ln(latents) compact
    f16* q_hi   = (f16*)alloc((size_t)BATCH * LQ * INDIM * 2);
    f16* q_lo   = (f16*)alloc((size_t)BATCH * LQ * INDIM * 2);
    f16* wq_t   = (f16*)alloc((size_t)INDIM * DM * 2);
    f16* wkv_t  = (f16*)alloc((size_t)DM * DM * 2);
    f16* wout_t = (f16*)alloc((size_t)DM * INDIM * 2);
    f16* attn_o = (f16*)alloc((size_t)BATCH * LQ * INDIM * 2);
    // split-K partials aliased into kv_in (4.33 MB << 67.6 MB):
    float* pO   = (float*)kv_in;                                   // 32*8*64*64 fp32 = 4.19 MB
    float* pm   = (float*)((char*)kv_in + (size_t)NBH * NCHUNK * 64 * 64 * 4);
    float* pl   = (float*)((char*)pm + (size_t)NBH * NCHUNK * 64 * 4);

    // weight transposes (fold q scale sqrt(64)=8 into Wq)
    transpose_w<<<dim3(INDIM / 32, DM / 32), 256, 0, stream>>>(Wq, wq_t, DM, INDIM, 8.0f);
    transpose_w<<<dim3(DM / 32, DM / 32), 256, 0, stream>>>(Wkv, wkv_t, DM, DM, 1.0f);
    transpose_w<<<dim3(DM / 32, INDIM / 32), 256, 0, stream>>>(Wout, wout_t, INDIM, DM, 1.0f);
    // layernorms
    ln_kernel<<<BATCH * MX, 256, 0, stream>>>(x, gm, bm, kv_in, nullptr, MX, 0);
    ln_kernel<<<BATCH * LQ, 256, 0, stream>>>(lat, gl, bl, kv_in, q_in, LQ, MX);
    // q = ln(latents) @ Wq * 8  -> hi/lo split
    gemm_bt<3><<<dim3(2, INDIM / 128), 256, 0, stream>>>(q_in, wq_t, q_hi, q_lo, nullptr, nullptr,
                                                         BATCH * LQ, INDIM, DM);
    // kv = [xn;ln] @ Wkv  (k -> hi/lo split, v -> vT)
    gemm_bt<2><<<dim3(MROWS / 128, DM / 128), 256, 0, stream>>>(kv_in, wkv_t, k_hi, k_lo, nullptr, vT,
                                                                MROWS, DM, DM);
    // attention: split-K partials (overwrite kv_in region — it is dead now) then merge
    attn_kernel<<<NBH * NCHUNK, 512, 0, stream>>>(q_hi, q_lo, k_hi, k_lo, vT, pO, pm, pl);
    attn_merge<<<NBH, 256, 0, stream>>>(pO, pm, pl, attn_o);
    // out = attn_o @ Wout
    gemm_bt<1><<<dim3(2, DM / 128), 256, 0, stream>>>(attn_o, wout_t, nullptr, nullptr, out, nullptr,
                                                      BATCH * LQ, DM, INDIM);
}